// Round 4
// baseline (500.269 us; speedup 1.0000x reference)
//
#include <hip/hip_runtime.h>

#define NN 50000
#define NE 800000

// ---------------- CSR build ----------------

__global__ __launch_bounds__(256) void k_count(const int* __restrict__ dst,
                                               int* __restrict__ cnt, int E) {
    int e = blockIdx.x * 256 + threadIdx.x;
    if (e < E) atomicAdd(&cnt[dst[e]], 1);
}

// merged exclusive scan over cnt[0..n) + dinv computation, one block.
// thread t owns the contiguous chunk [t*per, (t+1)*per); per-thread serial
// sum -> 1024-wide Hillis-Steele -> serial writeback. cnt is L2-hot (200KB).
#define SCAN_T 1024
__global__ __launch_bounds__(SCAN_T) void k_scan(const int* __restrict__ cnt,
                                                 int* __restrict__ rowstart,
                                                 float* __restrict__ dinv, int n) {
    __shared__ int s[SCAN_T];
    int t = threadIdx.x;
    int per = (n + SCAN_T - 1) / SCAN_T;
    int base = t * per;
    int sum = 0;
    for (int i = 0; i < per; ++i) {
        int g = base + i;
        if (g < n) sum += cnt[g];
    }
    s[t] = sum; __syncthreads();
    for (int off = 1; off < SCAN_T; off <<= 1) {
        int x = (t >= off) ? s[t - off] : 0;
        __syncthreads();
        s[t] += x; __syncthreads();
    }
    int run = s[t] - sum;            // exclusive prefix of this chunk
    for (int i = 0; i < per; ++i) {
        int g = base + i;
        if (g < n) {
            int cv = cnt[g];
            rowstart[g] = run;
            run += cv;
            // deg includes the self loop: cnt+1 (max(deg,1) automatic)
            dinv[g] = rsqrtf((float)cv + 1.0f);
        }
    }
}

__global__ __launch_bounds__(256) void k_scatter(const int* __restrict__ src,
                                                 const int* __restrict__ dst,
                                                 const int* __restrict__ rowstart,
                                                 int* __restrict__ cursor,
                                                 const float* __restrict__ dinv,
                                                 int2* __restrict__ csr, int E) {
    int e = blockIdx.x * 256 + threadIdx.x;
    if (e < E) {
        int s = src[e], d = dst[e];
        int p = rowstart[d] + atomicAdd(&cursor[d], 1);
        float w = dinv[s] * dinv[d];
        csr[p] = make_int2(s, __float_as_int(w));
    }
}

// ---------------- dense GEMM: T[n,F] = A[n,K] @ W[K,F] ----------------
// block = 256 threads = 4 waves; block covers 64 nodes.
// lane: fg = lane%16 -> 4 consecutive feats; ng = lane/16 -> 4-node group.
// per lane: 4 nodes x 4 feats register tile; W staged in LDS (stride 64).
// unroll 2: full unroll hoists 32x4 float4 loads -> 256 VGPR + spill (R2).

template <int K, int F>
__global__ __launch_bounds__(256) void k_gemm(const float* __restrict__ A,
                                              const float* __restrict__ W,
                                              float* __restrict__ T, int n) {
    __shared__ float wlds[K * 64];
    int tid = threadIdx.x;
    for (int i = tid; i < K * 64; i += 256) {
        int k = i >> 6, f = i & 63;
        wlds[i] = (f < F) ? W[k * F + f] : 0.0f;
    }
    __syncthreads();

    int lane = tid & 63, wid = tid >> 6;
    int fg = lane & 15, ng = lane >> 4;
    int nodebase = blockIdx.x * 64 + wid * 16 + ng * 4;

    float4 acc[4] = {};
    #pragma unroll 2
    for (int k = 0; k < K; k += 4) {
        float4 a[4];
        #pragma unroll
        for (int r = 0; r < 4; ++r) {
            int node = nodebase + r;
            a[r] = (node < n) ? *(const float4*)&A[node * K + k]
                              : float4{0.f, 0.f, 0.f, 0.f};
        }
        #pragma unroll
        for (int kk = 0; kk < 4; ++kk) {
            float4 wv = *(const float4*)&wlds[(k + kk) * 64 + fg * 4];
            #pragma unroll
            for (int r = 0; r < 4; ++r) {
                float av = (kk == 0) ? a[r].x : (kk == 1) ? a[r].y
                         : (kk == 2) ? a[r].z : a[r].w;
                acc[r].x += av * wv.x;
                acc[r].y += av * wv.y;
                acc[r].z += av * wv.z;
                acc[r].w += av * wv.w;
            }
        }
    }

    if (fg * 4 + 3 < F) {
        #pragma unroll
        for (int r = 0; r < 4; ++r) {
            int node = nodebase + r;
            if (node < n) *(float4*)&T[node * F + fg * 4] = acc[r];
        }
    }
}

// ---------------- normalized aggregation (gather over CSR) ----------------
// R3 restructure: 2 nodes per wave (one per half-wave), lane covers 2 feats
// via float2. One T-row load instruction serves 2 edges (one per half) ->
// instrs/edge halved, independent edge-streams per wave doubled (2xGB=32
// loads in flight). Row read per node = 32 lanes x 8B = 256B, coalesced.
// Tail predicated inside batch (w=0, col=0); streams of different length
// diverge via exec mask only.

#define GB 16

__global__ __launch_bounds__(256) void k_gather(const float* __restrict__ T,
                                                const int2* __restrict__ csr,
                                                const int* __restrict__ rowstart,
                                                const int* __restrict__ cnt,
                                                const float* __restrict__ dinv,
                                                const float* __restrict__ bias,
                                                float* __restrict__ OUT,
                                                int n, int F, int relu) {
    int tid = threadIdx.x;
    int wid = tid >> 6, lane = tid & 63;
    int half = lane >> 5, fl = lane & 31;
    int node = blockIdx.x * 8 + wid * 2 + half;
    if (node >= n) return;
    int f0 = fl * 2;
    bool factive = (f0 + 1) < F;      // F=40: lanes fl>=20 idle
    float di = dinv[node];

    float2 acc = {0.f, 0.f};
    if (factive) {
        float2 tv = *(const float2*)&T[node * F + f0];
        acc.x = tv.x * di * di;       // self loop
        acc.y = tv.y * di * di;
    }

    int s0 = rowstart[node], c = cnt[node];
    for (int j = 0; j < c; j += GB) {
        int   col[GB];
        float w[GB];
        #pragma unroll
        for (int u = 0; u < GB; ++u) {
            int idx = j + u;
            int2 cw = (idx < c) ? csr[s0 + idx] : make_int2(0, 0);
            col[u] = cw.x;
            w[u]   = __int_as_float(cw.y);   // 0 bits == 0.0f for tail
        }
        float2 tv[GB];
        #pragma unroll
        for (int u = 0; u < GB; ++u)
            tv[u] = factive ? *(const float2*)&T[col[u] * F + f0]
                            : make_float2(0.f, 0.f);
        #pragma unroll
        for (int u = 0; u < GB; ++u) {
            acc.x += w[u] * tv[u].x;
            acc.y += w[u] * tv[u].y;
        }
    }

    if (factive) {
        float2 b = *(const float2*)&bias[f0];
        float2 r = {acc.x + b.x, acc.y + b.y};
        if (relu) { r.x = fmaxf(r.x, 0.f); r.y = fmaxf(r.y, 0.f); }
        *(float2*)&OUT[node * F + f0] = r;
    }
}

// ---------------- launch ----------------

extern "C" void kernel_launch(void* const* d_in, const int* in_sizes, int n_in,
                              void* d_out, int out_size, void* d_ws, size_t ws_size,
                              hipStream_t stream) {
    const float* x  = (const float*)d_in[0];
    const int*   ei = (const int*)d_in[1];
    const float* W1 = (const float*)d_in[2];
    const float* b1 = (const float*)d_in[3];
    const float* W2 = (const float*)d_in[4];
    const float* b2 = (const float*)d_in[5];
    const float* W3 = (const float*)d_in[6];
    const float* b3 = (const float*)d_in[7];
    float* out = (float*)d_out;

    const int N = NN, E = NE;
    const int* src = ei;
    const int* dst = ei + E;

    // workspace layout (ws re-poisoned to 0xAA before every call)
    int*   cnt      = (int*)d_ws;                 // N
    int*   cursor   = cnt + N;                    // N  (adjacent to cnt: one memset)
    int*   rowstart = cursor + N;                 // N
    float* dinv     = (float*)(rowstart + N);     // N
    int2*  csr      = (int2*)(dinv + N);          // E pairs (col, norm-bits)
    float* tbuf     = (float*)(csr + E);          // N*64
    float* hbuf     = tbuf + (size_t)N * 64;      // N*64

    hipMemsetAsync(cnt, 0, sizeof(int) * 2 * N, stream);   // cnt + cursor

    int eb = (E + 255) / 256;       // 3125
    k_count  <<<eb, 256, 0, stream>>>(dst, cnt, E);
    k_scan   <<<1, SCAN_T, 0, stream>>>(cnt, rowstart, dinv, N);
    k_scatter<<<eb, 256, 0, stream>>>(src, dst, rowstart, cursor, dinv, csr, E);

    int gb = (N + 63) / 64;         // 782
    int ab = (N + 7) / 8;           // 6250

    k_gemm<128, 64><<<gb, 256, 0, stream>>>(x, W1, tbuf, N);
    k_gather<<<ab, 256, 0, stream>>>(tbuf, csr, rowstart, cnt, dinv, b1, hbuf, N, 64, 1);
    k_gemm<64, 64><<<gb, 256, 0, stream>>>(hbuf, W2, tbuf, N);
    k_gather<<<ab, 256, 0, stream>>>(tbuf, csr, rowstart, cnt, dinv, b2, hbuf, N, 64, 1);
    k_gemm<64, 40><<<gb, 256, 0, stream>>>(hbuf, W3, tbuf, N);
    k_gather<<<ab, 256, 0, stream>>>(tbuf, csr, rowstart, cnt, dinv, b3, out, N, 40, 0);
}

// Round 5
// 350.581 us; speedup vs baseline: 1.4270x; 1.4270x over previous
//
#include <hip/hip_runtime.h>
#include <hip/hip_fp16.h>

#define NN 50000
#define NE 800000

// ---------------- CSR build ----------------

__global__ __launch_bounds__(256) void k_count(const int* __restrict__ dst,
                                               int* __restrict__ cnt, int E) {
    int e = blockIdx.x * 256 + threadIdx.x;
    if (e < E) atomicAdd(&cnt[dst[e]], 1);
}

// R4 post-mortem: single-block merged scan was 123us (1 CU, uncoalesced
// serial chunks). Reverted to the 3-kernel scan (R3: ~12us total).

__global__ __launch_bounds__(256) void k_scan1(const int* __restrict__ cnt,
                                               int* __restrict__ rowstart,
                                               int* __restrict__ sums, int n) {
    __shared__ int s[256];
    int t = threadIdx.x, gid = blockIdx.x * 256 + t;
    int v = (gid < n) ? cnt[gid] : 0;
    s[t] = v; __syncthreads();
    for (int off = 1; off < 256; off <<= 1) {
        int x = (t >= off) ? s[t - off] : 0;
        __syncthreads();
        s[t] += x; __syncthreads();
    }
    if (gid < n) rowstart[gid] = s[t] - v;   // exclusive (partial, per-block)
    if (t == 255) sums[blockIdx.x] = s[t];
}

__global__ __launch_bounds__(256) void k_scan2(const int* __restrict__ sums,
                                               int* __restrict__ offs, int nb) {
    __shared__ int s[256];
    int t = threadIdx.x;
    int v = (t < nb) ? sums[t] : 0;
    s[t] = v; __syncthreads();
    for (int off = 1; off < 256; off <<= 1) {
        int x = (t >= off) ? s[t - off] : 0;
        __syncthreads();
        s[t] += x; __syncthreads();
    }
    offs[t] = s[t] - v;                      // exclusive scan of block sums
}

__global__ __launch_bounds__(256) void k_scan3(const int* __restrict__ cnt,
                                               int* __restrict__ rowstart,
                                               const int* __restrict__ offs,
                                               float* __restrict__ dinv, int n) {
    int gid = blockIdx.x * 256 + threadIdx.x;
    if (gid < n) {
        rowstart[gid] += offs[blockIdx.x];
        // deg includes the self loop: cnt + 1 (so max(deg,1) is automatic)
        dinv[gid] = rsqrtf((float)cnt[gid] + 1.0f);
    }
}

__global__ __launch_bounds__(256) void k_scatter(const int* __restrict__ src,
                                                 const int* __restrict__ dst,
                                                 const int* __restrict__ rowstart,
                                                 int* __restrict__ cursor,
                                                 const float* __restrict__ dinv,
                                                 int2* __restrict__ csr, int E) {
    int e = blockIdx.x * 256 + threadIdx.x;
    if (e < E) {
        int s = src[e], d = dst[e];
        int p = rowstart[d] + atomicAdd(&cursor[d], 1);
        float w = dinv[s] * dinv[d];
        csr[p] = make_int2(s, __float_as_int(w));
    }
}

// ---------------- dense GEMM: T[n,F] = A[n,K] @ W[K,F] ----------------
// A is fp32, accumulation fp32, OUTPUT staged fp16 (halves gather traffic;
// gather is L2-miss-traffic bound: R4 FETCH 84.5MB >> 12.8MB footprint).
// block = 256 threads = 4 waves; 64 nodes/block; W staged in LDS.
// unroll 2: full unroll hoists 32x4 float4 loads -> 256 VGPR + spill (R2).

template <int K, int F>
__global__ __launch_bounds__(256) void k_gemm(const float* __restrict__ A,
                                              const float* __restrict__ W,
                                              __half* __restrict__ T, int n) {
    __shared__ float wlds[K * 64];
    int tid = threadIdx.x;
    for (int i = tid; i < K * 64; i += 256) {
        int k = i >> 6, f = i & 63;
        wlds[i] = (f < F) ? W[k * F + f] : 0.0f;
    }
    __syncthreads();

    int lane = tid & 63, wid = tid >> 6;
    int fg = lane & 15, ng = lane >> 4;
    int nodebase = blockIdx.x * 64 + wid * 16 + ng * 4;

    float4 acc[4] = {};
    #pragma unroll 2
    for (int k = 0; k < K; k += 4) {
        float4 a[4];
        #pragma unroll
        for (int r = 0; r < 4; ++r) {
            int node = nodebase + r;
            a[r] = (node < n) ? *(const float4*)&A[node * K + k]
                              : float4{0.f, 0.f, 0.f, 0.f};
        }
        #pragma unroll
        for (int kk = 0; kk < 4; ++kk) {
            float4 wv = *(const float4*)&wlds[(k + kk) * 64 + fg * 4];
            #pragma unroll
            for (int r = 0; r < 4; ++r) {
                float av = (kk == 0) ? a[r].x : (kk == 1) ? a[r].y
                         : (kk == 2) ? a[r].z : a[r].w;
                acc[r].x += av * wv.x;
                acc[r].y += av * wv.y;
                acc[r].z += av * wv.z;
                acc[r].w += av * wv.w;
            }
        }
    }

    if (fg * 4 + 3 < F) {
        #pragma unroll
        for (int r = 0; r < 4; ++r) {
            int node = nodebase + r;
            if (node < n) {
                __half2 h[2];
                h[0] = __floats2half2_rn(acc[r].x, acc[r].y);
                h[1] = __floats2half2_rn(acc[r].z, acc[r].w);
                *(uint2*)&T[node * F + fg * 4] = *(uint2*)h;   // 8B store
            }
        }
    }
}

// ---------------- normalized aggregation (gather over CSR) ----------------
// 2 nodes per wave (one per half-wave), lane covers 2 feats via __half2.
// T rows are fp16: 32 lanes x 4B = 128B per row (1 cacheline). fp32 accum.
// Tail predicated inside batch (w=0, col=0).

#define GB 16

__global__ __launch_bounds__(256) void k_gather(const __half* __restrict__ T,
                                                const int2* __restrict__ csr,
                                                const int* __restrict__ rowstart,
                                                const int* __restrict__ cnt,
                                                const float* __restrict__ dinv,
                                                const float* __restrict__ bias,
                                                float* __restrict__ OUT,
                                                int n, int F, int relu) {
    int tid = threadIdx.x;
    int wid = tid >> 6, lane = tid & 63;
    int half = lane >> 5, fl = lane & 31;
    int node = blockIdx.x * 8 + wid * 2 + half;
    if (node >= n) return;
    int f0 = fl * 2;
    bool factive = (f0 + 1) < F;      // F=40: lanes fl>=20 idle
    float di = dinv[node];

    float2 acc = {0.f, 0.f};
    if (factive) {
        float2 tv = __half22float2(*(const __half2*)&T[node * F + f0]);
        acc.x = tv.x * di * di;       // self loop
        acc.y = tv.y * di * di;
    }

    int s0 = rowstart[node], c = cnt[node];
    for (int j = 0; j < c; j += GB) {
        int   col[GB];
        float w[GB];
        #pragma unroll
        for (int u = 0; u < GB; ++u) {
            int idx = j + u;
            int2 cw = (idx < c) ? csr[s0 + idx] : make_int2(0, 0);
            col[u] = cw.x;
            w[u]   = __int_as_float(cw.y);   // 0 bits == 0.0f for tail
        }
        __half2 tv[GB];
        #pragma unroll
        for (int u = 0; u < GB; ++u)
            tv[u] = factive ? *(const __half2*)&T[col[u] * F + f0]
                            : __half2{};
        #pragma unroll
        for (int u = 0; u < GB; ++u) {
            float2 tf = __half22float2(tv[u]);
            acc.x += w[u] * tf.x;
            acc.y += w[u] * tf.y;
        }
    }

    if (factive) {
        float2 b = *(const float2*)&bias[f0];
        float2 r = {acc.x + b.x, acc.y + b.y};
        if (relu) { r.x = fmaxf(r.x, 0.f); r.y = fmaxf(r.y, 0.f); }
        *(float2*)&OUT[node * F + f0] = r;
    }
}

// ---------------- launch ----------------

extern "C" void kernel_launch(void* const* d_in, const int* in_sizes, int n_in,
                              void* d_out, int out_size, void* d_ws, size_t ws_size,
                              hipStream_t stream) {
    const float* x  = (const float*)d_in[0];
    const int*   ei = (const int*)d_in[1];
    const float* W1 = (const float*)d_in[2];
    const float* b1 = (const float*)d_in[3];
    const float* W2 = (const float*)d_in[4];
    const float* b2 = (const float*)d_in[5];
    const float* W3 = (const float*)d_in[6];
    const float* b3 = (const float*)d_in[7];
    float* out = (float*)d_out;

    const int N = NN, E = NE;
    const int* src = ei;
    const int* dst = ei + E;

    // workspace layout (ws re-poisoned to 0xAA before every call)
    int*    cnt      = (int*)d_ws;                 // N
    int*    cursor   = cnt + N;                    // N  (adjacent: one memset)
    int*    rowstart = cursor + N;                 // N
    float*  dinv     = (float*)(rowstart + N);     // N
    int*    sums     = (int*)(dinv + N);           // 256
    int*    offs     = sums + 256;                 // 256
    int2*   csr      = (int2*)(offs + 256);        // E pairs (col, norm-bits)
    __half* tbuf     = (__half*)(csr + E);         // N*64 fp16 (GEMM->gather)
    float*  hbuf     = (float*)(tbuf + (size_t)N * 64);  // N*64 fp32 (gather->GEMM)

    hipMemsetAsync(cnt, 0, sizeof(int) * 2 * N, stream);   // cnt + cursor

    int eb = (E + 255) / 256;       // 3125
    int nb = (N + 255) / 256;       // 196
    k_count  <<<eb, 256, 0, stream>>>(dst, cnt, E);
    k_scan1  <<<nb, 256, 0, stream>>>(cnt, rowstart, sums, N);
    k_scan2  <<<1,  256, 0, stream>>>(sums, offs, nb);
    k_scan3  <<<nb, 256, 0, stream>>>(cnt, rowstart, offs, dinv, N);
    k_scatter<<<eb, 256, 0, stream>>>(src, dst, rowstart, cursor, dinv, csr, E);

    int gb = (N + 63) / 64;         // 782
    int ab = (N + 7) / 8;           // 6250

    k_gemm<128, 64><<<gb, 256, 0, stream>>>(x, W1, tbuf, N);
    k_gather<<<ab, 256, 0, stream>>>(tbuf, csr, rowstart, cnt, dinv, b1, hbuf, N, 64, 1);
    k_gemm<64, 64><<<gb, 256, 0, stream>>>(hbuf, W2, tbuf, N);
    k_gather<<<ab, 256, 0, stream>>>(tbuf, csr, rowstart, cnt, dinv, b2, hbuf, N, 64, 1);
    k_gemm<64, 40><<<gb, 256, 0, stream>>>(hbuf, W3, tbuf, N);
    k_gather<<<ab, 256, 0, stream>>>(tbuf, csr, rowstart, cnt, dinv, b3, out, N, 40, 0);
}

// Round 6
// 348.647 us; speedup vs baseline: 1.4349x; 1.0055x over previous
//
#include <hip/hip_runtime.h>
#include <hip/hip_fp16.h>

#define NN 50000
#define NE 800000

// ---------------- CSR build ----------------

__global__ __launch_bounds__(256) void k_count(const int* __restrict__ dst,
                                               int* __restrict__ cnt, int E) {
    int e = blockIdx.x * 256 + threadIdx.x;
    if (e < E) atomicAdd(&cnt[dst[e]], 1);
}

// 3-kernel scan (R4 taught us: single-block merged scan = 123us, 1 CU).

__global__ __launch_bounds__(256) void k_scan1(const int* __restrict__ cnt,
                                               int* __restrict__ rowstart,
                                               int* __restrict__ sums, int n) {
    __shared__ int s[256];
    int t = threadIdx.x, gid = blockIdx.x * 256 + t;
    int v = (gid < n) ? cnt[gid] : 0;
    s[t] = v; __syncthreads();
    for (int off = 1; off < 256; off <<= 1) {
        int x = (t >= off) ? s[t - off] : 0;
        __syncthreads();
        s[t] += x; __syncthreads();
    }
    if (gid < n) rowstart[gid] = s[t] - v;   // exclusive (partial, per-block)
    if (t == 255) sums[blockIdx.x] = s[t];
}

__global__ __launch_bounds__(256) void k_scan2(const int* __restrict__ sums,
                                               int* __restrict__ offs, int nb) {
    __shared__ int s[256];
    int t = threadIdx.x;
    int v = (t < nb) ? sums[t] : 0;
    s[t] = v; __syncthreads();
    for (int off = 1; off < 256; off <<= 1) {
        int x = (t >= off) ? s[t - off] : 0;
        __syncthreads();
        s[t] += x; __syncthreads();
    }
    offs[t] = s[t] - v;                      // exclusive scan of block sums
}

__global__ __launch_bounds__(256) void k_scan3(const int* __restrict__ cnt,
                                               int* __restrict__ rowstart,
                                               const int* __restrict__ offs,
                                               float* __restrict__ dinv, int n) {
    int gid = blockIdx.x * 256 + threadIdx.x;
    if (gid < n) {
        rowstart[gid] += offs[blockIdx.x];
        // deg includes the self loop: cnt + 1 (so max(deg,1) is automatic)
        dinv[gid] = rsqrtf((float)cnt[gid] + 1.0f);
    }
}

__global__ __launch_bounds__(256) void k_scatter(const int* __restrict__ src,
                                                 const int* __restrict__ dst,
                                                 const int* __restrict__ rowstart,
                                                 int* __restrict__ cursor,
                                                 const float* __restrict__ dinv,
                                                 int2* __restrict__ csr, int E) {
    int e = blockIdx.x * 256 + threadIdx.x;
    if (e < E) {
        int s = src[e], d = dst[e];
        int p = rowstart[d] + atomicAdd(&cursor[d], 1);
        float w = dinv[s] * dinv[d];
        csr[p] = make_int2(s, __float_as_int(w));
    }
}

// ---------------- dense GEMM: T[n,F] = A[n,K] @ W[K,F] ----------------
// R5 showed gemm<128,64> latency-bound: 782 blocks = 3/CU, 24.5% occupancy,
// 46us. R6: 32 nodes/block (grid 1563 = 6.1/CU), 2-node x 4-feat register
// tile per lane, unroll 4 (8 float4 A-loads in flight). K=128: 32KB LDS ->
// 5 blocks/CU resident (62%); K=64: 16KB -> grid-limited 6 (75%).
// A fp32, accum fp32, output staged fp16 (gather is L2-miss-traffic bound).

template <int K, int F>
__global__ __launch_bounds__(256) void k_gemm(const float* __restrict__ A,
                                              const float* __restrict__ W,
                                              __half* __restrict__ T, int n) {
    __shared__ float wlds[K * 64];
    int tid = threadIdx.x;
    for (int i = tid; i < K * 64; i += 256) {
        int k = i >> 6, f = i & 63;
        wlds[i] = (f < F) ? W[k * F + f] : 0.0f;
    }
    __syncthreads();

    int fg = tid & 15;            // feat group: feats fg*4 .. fg*4+3
    int nslot = tid >> 4;         // 16 node slots x 2 nodes
    int nodebase = blockIdx.x * 32 + nslot * 2;

    float4 acc[2] = {};
    #pragma unroll 4
    for (int k = 0; k < K; k += 4) {
        float4 a[2];
        #pragma unroll
        for (int r = 0; r < 2; ++r) {
            int node = nodebase + r;
            a[r] = (node < n) ? *(const float4*)&A[node * K + k]
                              : float4{0.f, 0.f, 0.f, 0.f};
        }
        #pragma unroll
        for (int kk = 0; kk < 4; ++kk) {
            float4 wv = *(const float4*)&wlds[(k + kk) * 64 + fg * 4];
            #pragma unroll
            for (int r = 0; r < 2; ++r) {
                float av = (kk == 0) ? a[r].x : (kk == 1) ? a[r].y
                         : (kk == 2) ? a[r].z : a[r].w;
                acc[r].x += av * wv.x;
                acc[r].y += av * wv.y;
                acc[r].z += av * wv.z;
                acc[r].w += av * wv.w;
            }
        }
    }

    if (fg * 4 + 3 < F) {
        #pragma unroll
        for (int r = 0; r < 2; ++r) {
            int node = nodebase + r;
            if (node < n) {
                __half2 h[2];
                h[0] = __floats2half2_rn(acc[r].x, acc[r].y);
                h[1] = __floats2half2_rn(acc[r].z, acc[r].w);
                *(uint2*)&T[node * F + fg * 4] = *(uint2*)h;   // 8B store
            }
        }
    }
}

// ---------------- normalized aggregation (gather over CSR) ----------------
// 2 nodes per wave (one per half-wave), lane covers 2 feats via __half2.
// T rows are fp16: 32 lanes x 4B = 128B per row (1 cacheline). fp32 accum.
// Tail predicated inside batch (w=0, col=0).

#define GB 16

__global__ __launch_bounds__(256) void k_gather(const __half* __restrict__ T,
                                                const int2* __restrict__ csr,
                                                const int* __restrict__ rowstart,
                                                const int* __restrict__ cnt,
                                                const float* __restrict__ dinv,
                                                const float* __restrict__ bias,
                                                float* __restrict__ OUT,
                                                int n, int F, int relu) {
    int tid = threadIdx.x;
    int wid = tid >> 6, lane = tid & 63;
    int half = lane >> 5, fl = lane & 31;
    int node = blockIdx.x * 8 + wid * 2 + half;
    if (node >= n) return;
    int f0 = fl * 2;
    bool factive = (f0 + 1) < F;      // F=40: lanes fl>=20 idle
    float di = dinv[node];

    float2 acc = {0.f, 0.f};
    if (factive) {
        float2 tv = __half22float2(*(const __half2*)&T[node * F + f0]);
        acc.x = tv.x * di * di;       // self loop
        acc.y = tv.y * di * di;
    }

    int s0 = rowstart[node], c = cnt[node];
    for (int j = 0; j < c; j += GB) {
        int   col[GB];
        float w[GB];
        #pragma unroll
        for (int u = 0; u < GB; ++u) {
            int idx = j + u;
            int2 cw = (idx < c) ? csr[s0 + idx] : make_int2(0, 0);
            col[u] = cw.x;
            w[u]   = __int_as_float(cw.y);   // 0 bits == 0.0f for tail
        }
        __half2 tv[GB];
        #pragma unroll
        for (int u = 0; u < GB; ++u)
            tv[u] = factive ? *(const __half2*)&T[col[u] * F + f0]
                            : __half2{};
        #pragma unroll
        for (int u = 0; u < GB; ++u) {
            float2 tf = __half22float2(tv[u]);
            acc.x += w[u] * tf.x;
            acc.y += w[u] * tf.y;
        }
    }

    if (factive) {
        float2 b = *(const float2*)&bias[f0];
        float2 r = {acc.x + b.x, acc.y + b.y};
        if (relu) { r.x = fmaxf(r.x, 0.f); r.y = fmaxf(r.y, 0.f); }
        *(float2*)&OUT[node * F + f0] = r;
    }
}

// ---------------- launch ----------------

extern "C" void kernel_launch(void* const* d_in, const int* in_sizes, int n_in,
                              void* d_out, int out_size, void* d_ws, size_t ws_size,
                              hipStream_t stream) {
    const float* x  = (const float*)d_in[0];
    const int*   ei = (const int*)d_in[1];
    const float* W1 = (const float*)d_in[2];
    const float* b1 = (const float*)d_in[3];
    const float* W2 = (const float*)d_in[4];
    const float* b2 = (const float*)d_in[5];
    const float* W3 = (const float*)d_in[6];
    const float* b3 = (const float*)d_in[7];
    float* out = (float*)d_out;

    const int N = NN, E = NE;
    const int* src = ei;
    const int* dst = ei + E;

    // workspace layout (ws re-poisoned to 0xAA before every call)
    int*    cnt      = (int*)d_ws;                 // N
    int*    cursor   = cnt + N;                    // N  (adjacent: one memset)
    int*    rowstart = cursor + N;                 // N
    float*  dinv     = (float*)(rowstart + N);     // N
    int*    sums     = (int*)(dinv + N);           // 256
    int*    offs     = sums + 256;                 // 256
    int2*   csr      = (int2*)(offs + 256);        // E pairs (col, norm-bits)
    __half* tbuf     = (__half*)(csr + E);         // N*64 fp16 (GEMM->gather)
    float*  hbuf     = (float*)(tbuf + (size_t)N * 64);  // N*64 fp32 (gather->GEMM)

    hipMemsetAsync(cnt, 0, sizeof(int) * 2 * N, stream);   // cnt + cursor

    int eb = (E + 255) / 256;       // 3125
    int nb = (N + 255) / 256;       // 196
    k_count  <<<eb, 256, 0, stream>>>(dst, cnt, E);
    k_scan1  <<<nb, 256, 0, stream>>>(cnt, rowstart, sums, N);
    k_scan2  <<<1,  256, 0, stream>>>(sums, offs, nb);
    k_scan3  <<<nb, 256, 0, stream>>>(cnt, rowstart, offs, dinv, N);
    k_scatter<<<eb, 256, 0, stream>>>(src, dst, rowstart, cursor, dinv, csr, E);

    int gb = (N + 31) / 32;         // 1563
    int ab = (N + 7) / 8;           // 6250

    k_gemm<128, 64><<<gb, 256, 0, stream>>>(x, W1, tbuf, N);
    k_gather<<<ab, 256, 0, stream>>>(tbuf, csr, rowstart, cnt, dinv, b1, hbuf, N, 64, 1);
    k_gemm<64, 64><<<gb, 256, 0, stream>>>(hbuf, W2, tbuf, N);
    k_gather<<<ab, 256, 0, stream>>>(tbuf, csr, rowstart, cnt, dinv, b2, hbuf, N, 64, 1);
    k_gemm<64, 40><<<gb, 256, 0, stream>>>(hbuf, W3, tbuf, N);
    k_gather<<<ab, 256, 0, stream>>>(tbuf, csr, rowstart, cnt, dinv, b3, out, N, 40, 0);
}

// Round 7
// 319.291 us; speedup vs baseline: 1.5668x; 1.0919x over previous
//
#include <hip/hip_runtime.h>
#include <hip/hip_fp16.h>

#define NN 50000
#define NE 800000

// ======== gemm1 (x@W1 -> fp16 T) merged with edge count (independent) ====
// Blocks [0,gemmBlocks): 32 nodes/block, 2-node x 4-feat reg tile, unroll 4.
// Blocks [gemmBlocks, ...): histogram of dst. They were serialized as two
// stream-ordered kernels before; merged = concurrent + one less gap.

__global__ __launch_bounds__(256) void k_gemm1_count(
    const float* __restrict__ A, const float* __restrict__ W,
    __half* __restrict__ T, int n,
    const int* __restrict__ dst, int* __restrict__ cnt, int E, int gemmBlocks)
{
    __shared__ float wlds[128 * 64];     // 32KB (count blocks simply ignore)
    int tid = threadIdx.x;

    if ((int)blockIdx.x >= gemmBlocks) {
        int e = ((int)blockIdx.x - gemmBlocks) * 256 + tid;
        if (e < E) atomicAdd(&cnt[dst[e]], 1);
        return;
    }

    const int K = 128;
    for (int i = tid; i < K * 64; i += 256) wlds[i] = W[i];   // F=64: direct
    __syncthreads();

    int fg = tid & 15;            // feats fg*4 .. fg*4+3
    int nslot = tid >> 4;
    int nodebase = blockIdx.x * 32 + nslot * 2;

    float4 acc[2] = {};
    #pragma unroll 4
    for (int k = 0; k < K; k += 4) {
        float4 a[2];
        #pragma unroll
        for (int r = 0; r < 2; ++r) {
            int node = nodebase + r;
            a[r] = (node < n) ? *(const float4*)&A[node * K + k]
                              : float4{0.f, 0.f, 0.f, 0.f};
        }
        #pragma unroll
        for (int kk = 0; kk < 4; ++kk) {
            float4 wv = *(const float4*)&wlds[(k + kk) * 64 + fg * 4];
            #pragma unroll
            for (int r = 0; r < 2; ++r) {
                float av = (kk == 0) ? a[r].x : (kk == 1) ? a[r].y
                         : (kk == 2) ? a[r].z : a[r].w;
                acc[r].x += av * wv.x;
                acc[r].y += av * wv.y;
                acc[r].z += av * wv.z;
                acc[r].w += av * wv.w;
            }
        }
    }
    #pragma unroll
    for (int r = 0; r < 2; ++r) {
        int node = nodebase + r;
        if (node < n) {
            __half2 h[2];
            h[0] = __floats2half2_rn(acc[r].x, acc[r].y);
            h[1] = __floats2half2_rn(acc[r].z, acc[r].w);
            *(uint2*)&T[node * 64 + fg * 4] = *(uint2*)h;
        }
    }
}

// ======== scan (3-kernel scan collapsed to 2; R4: 1-block scan = 123us) ===

__global__ __launch_bounds__(256) void k_scan1(const int* __restrict__ cnt,
                                               int* __restrict__ rowstart,
                                               int* __restrict__ sums, int n) {
    __shared__ int s[256];
    int t = threadIdx.x, gid = blockIdx.x * 256 + t;
    int v = (gid < n) ? cnt[gid] : 0;
    s[t] = v; __syncthreads();
    for (int off = 1; off < 256; off <<= 1) {
        int x = (t >= off) ? s[t - off] : 0;
        __syncthreads();
        s[t] += x; __syncthreads();
    }
    if (gid < n) rowstart[gid] = s[t] - v;   // block-local exclusive
    if (t == 255) sums[blockIdx.x] = s[t];
}

// block b adds prefix = sum(sums[0..b)) and computes dinv. nb<=256.
__global__ __launch_bounds__(256) void k_scan23(const int* __restrict__ sums,
                                                int* __restrict__ rowstart,
                                                const int* __restrict__ cnt,
                                                float* __restrict__ dinv, int n) {
    __shared__ int s[256];
    int t = threadIdx.x, b = blockIdx.x;
    s[t] = (t < b) ? sums[t] : 0;
    __syncthreads();
    for (int off = 128; off > 0; off >>= 1) {
        if (t < off) s[t] += s[t + off];
        __syncthreads();
    }
    int prefix = s[0];
    int gid = b * 256 + t;
    if (gid < n) {
        rowstart[gid] += prefix;
        dinv[gid] = rsqrtf((float)cnt[gid] + 1.0f);   // deg incl. self loop
    }
}

__global__ __launch_bounds__(256) void k_scatter(const int* __restrict__ src,
                                                 const int* __restrict__ dst,
                                                 const int* __restrict__ rowstart,
                                                 int* __restrict__ cursor,
                                                 const float* __restrict__ dinv,
                                                 int2* __restrict__ csr, int E) {
    int e = blockIdx.x * 256 + threadIdx.x;
    if (e < E) {
        int s = src[e], d = dst[e];
        int p = rowstart[d] + atomicAdd(&cursor[d], 1);
        float w = dinv[s] * dinv[d];
        csr[p] = make_int2(s, __float_as_int(w));
    }
}

// ======== fused: gather (bias_in + relu) then @W (64 x F_OUT) -> fp16 ====
// 8 nodes/block (4 waves x 2 per wave). Gather as before (fp16 rows, fp32
// accum). Aggregated row round-trips through LDS g[8][64]; each half-wave
// reads only its own row (plus __syncthreads for safety). W k-major in LDS,
// lane fl reads W[k][2fl..2fl+1] as float2 (2-way bank alias = free), g via
// ds_read_b128 broadcast. GEMM LDS/VALU work hides under other waves'
// gather-miss latency.

#define GB 16

template <int F_OUT>
__global__ __launch_bounds__(256) void k_fused(
    const __half* __restrict__ Tin, const int2* __restrict__ csr,
    const int* __restrict__ rowstart, const int* __restrict__ cnt,
    const float* __restrict__ dinv, const float* __restrict__ bias_in,
    const float* __restrict__ W, __half* __restrict__ Tout, int n)
{
    __shared__ float wlds[64 * F_OUT];
    __shared__ float g[8 * 64];
    int tid = threadIdx.x;
    for (int i = tid; i < 64 * F_OUT; i += 256) wlds[i] = W[i];  // k-major

    int wid = tid >> 6, lane = tid & 63;
    int half = lane >> 5, fl = lane & 31;
    int slot = wid * 2 + half;
    int node = blockIdx.x * 8 + slot;
    bool valid = node < n;

    float2 acc = {0.f, 0.f};
    if (valid) {
        float di = dinv[node];
        float2 tv = __half22float2(*(const __half2*)&Tin[node * 64 + fl * 2]);
        acc.x = tv.x * di * di;                    // self loop
        acc.y = tv.y * di * di;
        int s0 = rowstart[node], c = cnt[node];
        for (int j = 0; j < c; j += GB) {
            int   col[GB];
            float w[GB];
            #pragma unroll
            for (int u = 0; u < GB; ++u) {
                int idx = j + u;
                int2 cw = (idx < c) ? csr[s0 + idx] : make_int2(0, 0);
                col[u] = cw.x;
                w[u]   = __int_as_float(cw.y);
            }
            __half2 tv2[GB];
            #pragma unroll
            for (int u = 0; u < GB; ++u)
                tv2[u] = *(const __half2*)&Tin[col[u] * 64 + fl * 2];
            #pragma unroll
            for (int u = 0; u < GB; ++u) {
                float2 tf = __half22float2(tv2[u]);
                acc.x += w[u] * tf.x;
                acc.y += w[u] * tf.y;
            }
        }
        float2 b = *(const float2*)&bias_in[fl * 2];
        acc.x = fmaxf(acc.x + b.x, 0.f);           // relu (both fused layers)
        acc.y = fmaxf(acc.y + b.y, 0.f);
        *(float2*)&g[slot * 64 + fl * 2] = acc;
    }
    __syncthreads();    // also covers the W staging at the top

    if (valid && (fl * 2 + 1) < F_OUT) {
        float2 o = {0.f, 0.f};
        #pragma unroll 4
        for (int k = 0; k < 64; k += 4) {
            float4 gv = *(const float4*)&g[slot * 64 + k];
            #pragma unroll
            for (int kk = 0; kk < 4; ++kk) {
                float2 wv = *(const float2*)&wlds[(k + kk) * F_OUT + fl * 2];
                float gk = (kk == 0) ? gv.x : (kk == 1) ? gv.y
                         : (kk == 2) ? gv.z : gv.w;
                o.x += gk * wv.x;
                o.y += gk * wv.y;
            }
        }
        __half2 h = __floats2half2_rn(o.x, o.y);
        *(uint*)&Tout[node * F_OUT + fl * 2] = *(uint*)&h;
    }
}

// ======== final gather: fp16 Tin (F=40) -> +b3 -> fp32 out ========

__global__ __launch_bounds__(256) void k_gather_out(
    const __half* __restrict__ T, const int2* __restrict__ csr,
    const int* __restrict__ rowstart, const int* __restrict__ cnt,
    const float* __restrict__ dinv, const float* __restrict__ bias,
    float* __restrict__ OUT, int n, int F)
{
    int tid = threadIdx.x;
    int wid = tid >> 6, lane = tid & 63;
    int half = lane >> 5, fl = lane & 31;
    int node = blockIdx.x * 8 + wid * 2 + half;
    if (node >= n) return;
    int f0 = fl * 2;
    bool factive = (f0 + 1) < F;
    float di = dinv[node];

    float2 acc = {0.f, 0.f};
    if (factive) {
        float2 tv = __half22float2(*(const __half2*)&T[node * F + f0]);
        acc.x = tv.x * di * di;
        acc.y = tv.y * di * di;
    }
    int s0 = rowstart[node], c = cnt[node];
    for (int j = 0; j < c; j += GB) {
        int   col[GB];
        float w[GB];
        #pragma unroll
        for (int u = 0; u < GB; ++u) {
            int idx = j + u;
            int2 cw = (idx < c) ? csr[s0 + idx] : make_int2(0, 0);
            col[u] = cw.x;
            w[u]   = __int_as_float(cw.y);
        }
        __half2 tv[GB];
        #pragma unroll
        for (int u = 0; u < GB; ++u)
            tv[u] = factive ? *(const __half2*)&T[col[u] * F + f0] : __half2{};
        #pragma unroll
        for (int u = 0; u < GB; ++u) {
            float2 tf = __half22float2(tv[u]);
            acc.x += w[u] * tf.x;
            acc.y += w[u] * tf.y;
        }
    }
    if (factive) {
        float2 b = *(const float2*)&bias[f0];
        *(float2*)&OUT[node * F + f0] = make_float2(acc.x + b.x, acc.y + b.y);
    }
}

// ---------------- launch ----------------

extern "C" void kernel_launch(void* const* d_in, const int* in_sizes, int n_in,
                              void* d_out, int out_size, void* d_ws, size_t ws_size,
                              hipStream_t stream) {
    const float* x  = (const float*)d_in[0];
    const int*   ei = (const int*)d_in[1];
    const float* W1 = (const float*)d_in[2];
    const float* b1 = (const float*)d_in[3];
    const float* W2 = (const float*)d_in[4];
    const float* b2 = (const float*)d_in[5];
    const float* W3 = (const float*)d_in[6];
    const float* b3 = (const float*)d_in[7];
    float* out = (float*)d_out;

    const int N = NN, E = NE;
    const int* src = ei;
    const int* dst = ei + E;

    // workspace (re-poisoned to 0xAA before every call)
    int*    cnt      = (int*)d_ws;                       // N
    int*    cursor   = cnt + N;                          // N (one memset)
    int*    rowstart = cursor + N;                       // N
    float*  dinv     = (float*)(rowstart + N);           // N
    int*    sums     = (int*)(dinv + N);                 // 256
    int2*   csr      = (int2*)(sums + 256);              // E
    __half* tA       = (__half*)(csr + E);               // N*64 fp16
    __half* tB       = tA + (size_t)N * 64;              // N*64 fp16
    __half* tC       = tB + (size_t)N * 64;              // N*40 fp16

    hipMemsetAsync(cnt, 0, sizeof(int) * 2 * N, stream);

    int eb = (E + 255) / 256;       // 3125
    int nb = (N + 255) / 256;       // 196
    int gb = (N + 31) / 32;         // 1563
    int fb = (N + 7) / 8;           // 6250

    k_gemm1_count<<<gb + eb, 256, 0, stream>>>(x, W1, tA, N, dst, cnt, E, gb);
    k_scan1 <<<nb, 256, 0, stream>>>(cnt, rowstart, sums, N);
    k_scan23<<<nb, 256, 0, stream>>>(sums, rowstart, cnt, dinv, N);
    k_scatter<<<eb, 256, 0, stream>>>(src, dst, rowstart, cursor, dinv, csr, E);

    k_fused<64><<<fb, 256, 0, stream>>>(tA, csr, rowstart, cnt, dinv, b1, W2, tB, N);
    k_fused<40><<<fb, 256, 0, stream>>>(tB, csr, rowstart, cnt, dinv, b2, W3, tC, N);
    k_gather_out<<<fb, 256, 0, stream>>>(tC, csr, rowstart, cnt, dinv, b3, out, N, 40);
}